// Round 7
// baseline (9038.943 us; speedup 1.0000x reference)
//
#include <hip/hip_runtime.h>
#include <math.h>

typedef __attribute__((ext_vector_type(2))) double f64x2;
typedef __attribute__((ext_vector_type(4))) double f64x4;
typedef __attribute__((ext_vector_type(2))) float f32x2;
typedef __attribute__((ext_vector_type(4))) float f32x4;

// ---------------- probe: discover v_mfma_f64_16x16x4 D-fragment mapping --------
// A[m][k] = 1+m+17k, B[k][n] = 2+3k+5n (asymmetric, exact small ints).
// Candidate D mappings (g=lane>>4, c=lane&15, reg r):
//   1: D[4g+r][c]   2: D[g+4r][c]   3: D[c][4g+r]   4: D[c][g+4r]
// flag = matching mapping, or 0 -> conv2 uses VALU fallback (always correct).
__global__ __launch_bounds__(64) void k_probe(int* __restrict__ flag) {
  int l = threadIdx.x;
  int g = l >> 4, c = l & 15;
  double a = 1.0 + (double)(l & 15) + 17.0 * (double)(l >> 4);    // A[m=l%16][k=l/16]
  double b = 2.0 + 3.0 * (double)(l >> 4) + 5.0 * (double)(l & 15); // B[k=l/16][n=l%16]
  f64x4 d = {0.0, 0.0, 0.0, 0.0};
  d = __builtin_amdgcn_mfma_f64_16x16x4f64(a, b, d, 0, 0, 0);
  auto ref = [](int R, int C) -> double {
    double s = 0.0;
    for (int k = 0; k < 4; k++) s += (1.0 + R + 17.0 * k) * (2.0 + 3.0 * k + 5.0 * C);
    return s;
  };
  int ok1 = 1, ok2 = 1, ok3 = 1, ok4 = 1;
#pragma unroll
  for (int r = 0; r < 4; r++) {
    double v = d[r];
    ok1 &= (v == ref(g * 4 + r, c));
    ok2 &= (v == ref(g + 4 * r, c));
    ok3 &= (v == ref(c, g * 4 + r));
    ok4 &= (v == ref(c, g + 4 * r));
  }
  ok1 = __all(ok1); ok2 = __all(ok2); ok3 = __all(ok3); ok4 = __all(ok4);
  if (l == 0) *flag = ok1 ? 1 : (ok2 ? 2 : (ok3 ? 3 : (ok4 ? 4 : 0)));
}

// ---------------- Wp -> wT fp32, layout [k][n], k=(ky*9+kx)*256+ci --------------
__global__ __launch_bounds__(256) void k_wkn(const float* __restrict__ Wp,
                                             float* __restrict__ wT) {
  const int total = 20736 * 256;
  for (int gid = blockIdx.x * 256 + threadIdx.x; gid < total; gid += gridDim.x * 256) {
    int k = gid >> 8, n = gid & 255;
    int t = k >> 8, ci = k & 255;
    wT[gid] = Wp[(size_t)n * 20736 + ci * 81 + t];
  }
}

// ---------------- Conv1: 1->256 k9 s1, fp64, out [img][y][x][256], 19x19 --------
__global__ __launch_bounds__(256) void k_conv1_19(const float* __restrict__ x,
                                                  const float* __restrict__ Wc,
                                                  const float* __restrict__ bc,
                                                  double* __restrict__ h) {
  int b = blockIdx.x >> 1;
  int rh = (blockIdx.x & 1) * 10;
  int re = rh ? 19 : 10;
  int oc = threadIdx.x;
  __shared__ float xs[784];
  for (int i = threadIdx.x; i < 784; i += 256) xs[i] = x[(size_t)b * 784 + i];
  __syncthreads();
  float w[81];
#pragma unroll
  for (int t = 0; t < 81; t++) w[t] = Wc[(size_t)oc * 81 + t];
  double bias = (double)bc[oc];
  for (int oh = rh; oh < re; oh++) {
    for (int ow4 = 0; ow4 < 20; ow4 += 4) {
      double a0 = bias, a1 = bias, a2 = bias, a3 = bias;
#pragma unroll
      for (int ky = 0; ky < 9; ky++) {
        const float* xr = &xs[(oh + ky) * 28 + ow4];
#pragma unroll
        for (int kx = 0; kx < 9; kx++) {
          double wv = (double)w[ky * 9 + kx];
          a0 += wv * (double)xr[kx + 0];
          a1 += wv * (double)xr[kx + 1];
          a2 += wv * (double)xr[kx + 2];
          a3 += wv * (double)xr[kx + 3];
        }
      }
      size_t base = ((size_t)(b * 19 + oh) * 19 + ow4) * 256 + oc;
      h[base + 0]   = fmax(a0, 0.0);
      h[base + 256] = fmax(a1, 0.0);
      h[base + 512] = fmax(a2, 0.0);
      if (ow4 < 16) h[base + 768] = fmax(a3, 0.0);  // skip col 19
    }
  }
}

// ---------------- Conv2: f64 MFMA implicit GEMM with probed D-map ---------------
// Tile 32m x 64n, 128 thr (2 waves, each 16m x 64n = 4 MFMA n-tiles).
// Grid thirds: dim3(192,4) = 768 blocks = exactly 3 blocks/CU (6 waves/CU).
// LDS: A f64 [k][m] (pad 34), B fp32 [k][n] (pad 68; fp32 exact for wT values).
// MFMA-bound by construction: 16 mfma/ks/wave (64 cyc each) vs ~140 LDS cyc/ks.
// flag==0 -> VALU fallback path (same staging, plain fma, always correct).
__global__ __launch_bounds__(128) void k_conv2_m(const double* __restrict__ h,
                                                 const float* __restrict__ wT,
                                                 double* __restrict__ uraw,
                                                 const int* __restrict__ flagp,
                                                 int mG0, int imgLo) {
  __shared__ __align__(16) double As[2][16][34];
  __shared__ __align__(16) float Bs[2][16][68];
  int tid = threadIdx.x;
  int m0 = blockIdx.x * 32, n0 = blockIdx.y * 64;

  // A staging: thread -> (m row, 4 consecutive k)
  int ma = tid & 31, kqa = tid >> 5;
  int mGa = mG0 + m0 + ma;
  int imga = mGa / 36, spa = mGa % 36;
  size_t abase = ((size_t)((imga - imgLo) * 361 + (spa / 6) * 38 + (spa % 6) * 2)) * 256;
  const double* hrow = h + abase;
  // B staging: thread -> (k row, 8 consecutive n)
  int kb = tid >> 3, n8 = (tid & 7) * 8;
  // fragment coords
  int w = tid >> 6, lane = tid & 63;
  int fl = lane & 15, fk = lane >> 4;
  int flag = *flagp;  // uniform

  f64x2 pa0, pa1;
  f32x4 pb0, pb1;
  auto loadreg = [&](int ks) {
    int t = ks >> 4, ci0 = (ks & 15) * 16;
    const double* ga = hrow + (size_t)((t / 9) * 19 + (t % 9)) * 256 + ci0 + kqa * 4;
    pa0 = *(const f64x2*)ga;
    pa1 = *(const f64x2*)(ga + 2);
    const float* gb = wT + (size_t)(ks * 16 + kb) * 256 + n0 + n8;
    pb0 = *(const f32x4*)gb;
    pb1 = *(const f32x4*)(gb + 4);
  };
  auto writebuf = [&](int buf) {
    As[buf][kqa * 4 + 0][ma] = pa0.x;
    As[buf][kqa * 4 + 1][ma] = pa0.y;
    As[buf][kqa * 4 + 2][ma] = pa1.x;
    As[buf][kqa * 4 + 3][ma] = pa1.y;
    *(f32x4*)&Bs[buf][kb][n8] = pb0;
    *(f32x4*)&Bs[buf][kb][n8 + 4] = pb1;
  };

  loadreg(0);
  writebuf(0);
  loadreg(1);
  __syncthreads();

  if (flag) {
    f64x4 acc0 = {0, 0, 0, 0}, acc1 = {0, 0, 0, 0}, acc2 = {0, 0, 0, 0}, acc3 = {0, 0, 0, 0};
    int mwl = w * 16 + fl;
    int cur = 0;
    for (int ks = 0; ks < 1296; ks++) {
      if (ks + 1 < 1296) writebuf(cur ^ 1);  // safe: end-of-prev-iter barrier ordered reads
      if (ks + 2 < 1296) loadreg(ks + 2);
#pragma unroll
      for (int kq = 0; kq < 4; kq++) {
        double a = As[cur][kq * 4 + fk][mwl];
        double b0 = (double)Bs[cur][kq * 4 + fk][fl];
        double b1 = (double)Bs[cur][kq * 4 + fk][16 + fl];
        double b2 = (double)Bs[cur][kq * 4 + fk][32 + fl];
        double b3 = (double)Bs[cur][kq * 4 + fk][48 + fl];
        acc0 = __builtin_amdgcn_mfma_f64_16x16x4f64(a, b0, acc0, 0, 0, 0);
        acc1 = __builtin_amdgcn_mfma_f64_16x16x4f64(a, b1, acc1, 0, 0, 0);
        acc2 = __builtin_amdgcn_mfma_f64_16x16x4f64(a, b2, acc2, 0, 0, 0);
        acc3 = __builtin_amdgcn_mfma_f64_16x16x4f64(a, b3, acc3, 0, 0, 0);
      }
      __syncthreads();
      cur ^= 1;
    }
    f64x4 accs[4] = {acc0, acc1, acc2, acc3};
#pragma unroll
    for (int nt = 0; nt < 4; nt++) {
#pragma unroll
      for (int r = 0; r < 4; r++) {
        int rb = (flag == 1 || flag == 3) ? (fk * 4 + r) : (fk + 4 * r);
        int R = (flag <= 2) ? rb : fl;
        int C = (flag <= 2) ? fl : rb;
        int mG = mG0 + m0 + w * 16 + R;
        int img = mG / 36, sp = mG % 36;
        int n = n0 + nt * 16 + C;
        uraw[(size_t)img * 9216 + (size_t)n * 36 + sp] = accs[nt][r];
      }
    }
  } else {
    // VALU fallback: thread tile 2m x 8n
    int ty = tid >> 3, tx = tid & 7;
    double acc[2][8];
#pragma unroll
    for (int i = 0; i < 2; i++)
#pragma unroll
      for (int j = 0; j < 8; j++) acc[i][j] = 0.0;
    int cur = 0;
    for (int ks = 0; ks < 1296; ks++) {
      if (ks + 1 < 1296) writebuf(cur ^ 1);
      if (ks + 2 < 1296) loadreg(ks + 2);
#pragma unroll
      for (int kk = 0; kk < 16; kk++) {
        f64x2 av = *(const f64x2*)&As[cur][kk][ty * 2];
        f32x4 bv0 = *(const f32x4*)&Bs[cur][kk][tx * 8];
        f32x4 bv1 = *(const f32x4*)&Bs[cur][kk][tx * 8 + 4];
        double bd[8] = {(double)bv0.x, (double)bv0.y, (double)bv0.z, (double)bv0.w,
                        (double)bv1.x, (double)bv1.y, (double)bv1.z, (double)bv1.w};
#pragma unroll
        for (int j = 0; j < 8; j++) {
          acc[0][j] = fma(av.x, bd[j], acc[0][j]);
          acc[1][j] = fma(av.y, bd[j], acc[1][j]);
        }
      }
      __syncthreads();
      cur ^= 1;
    }
#pragma unroll
    for (int i = 0; i < 2; i++) {
      int mG = mG0 + m0 + ty * 2 + i;
      int img = mG / 36, sp = mG % 36;
#pragma unroll
      for (int j = 0; j < 8; j++) {
        int n = n0 + tx * 8 + j;
        uraw[(size_t)img * 9216 + (size_t)n * 36 + sp] = acc[i][j];
      }
    }
  }
}

// ---------------- squash of primary capsules, fp64, IN PLACE --------------------
__global__ __launch_bounds__(256) void k_squash_ip(double* __restrict__ u,
                                                   const float* __restrict__ bp) {
  int idx = blockIdx.x * 256 + threadIdx.x;  // (b,c): 512*1152
  int bl = idx / 1152, c = idx % 1152;
  size_t base = ((size_t)bl * 1152 + c) * 8;
  double v[8];
  double ns = 0.0;
#pragma unroll
  for (int i = 0; i < 8; i++) {
    int f = c * 8 + i;
    int ch = f / 36;
    double val = u[base + i] + (double)bp[ch];
    v[i] = val;
    ns += val * val;
  }
  double sc = (ns / (1.0 + ns)) / (0.001 + sqrt(ns));
#pragma unroll
  for (int i = 0; i < 8; i++) u[base + i] = v[i] * sc;
}

// ---------------- u_hat fp64, eighth batch (bl in [0,64)) -----------------------
__global__ __launch_bounds__(320) void k_uhat64(const double* __restrict__ u,
                                                const float* __restrict__ Wd,
                                                double* __restrict__ uhat, int b0) {
  int c = blockIdx.x;
  int t = threadIdx.x;
  int jo = t % 160, half = t / 160;
  double w[8];
#pragma unroll
  for (int i = 0; i < 8; i++) w[i] = (double)Wd[((size_t)c * 160 + jo) * 8 + i];
  for (int it = 0; it < 32; it++) {
    int bl = it * 2 + half;
    const double* up = u + ((size_t)(b0 + bl) * 1152 + c) * 8;
    double s = 0.0;
#pragma unroll
    for (int i = 0; i < 8; i++) s += w[i] * up[i];
    uhat[((size_t)bl * 1152 + c) * 160 + jo] = s;
  }
}

// ---------------- c_ij = softmax(b_ij) fp64, wide grid --------------------------
__global__ __launch_bounds__(192) void k_cij(const double* __restrict__ bij,
                                             double* __restrict__ cij) {
  int bl = blockIdx.x;
  int c = blockIdx.y * 192 + threadIdx.x;  // 6*192 = 1152
  const double* bp_ = bij + ((size_t)bl * 1152 + c) * 10;
  double bv[10], mx = -1e300;
#pragma unroll
  for (int j = 0; j < 10; j++) { bv[j] = bp_[j]; mx = fmax(mx, bv[j]); }
  double s = 0.0;
#pragma unroll
  for (int j = 0; j < 10; j++) { bv[j] = exp(bv[j] - mx); s += bv[j]; }
  double inv = 1.0 / s;
  double* cp = cij + ((size_t)bl * 1152 + c) * 10;
#pragma unroll
  for (int j = 0; j < 10; j++) cp[j] = bv[j] * inv;
}

// ---------------- routing s_j pass fp64, wide coalesced grid (bl x j) -----------
template <int IT>
__global__ __launch_bounds__(256) void k_route_s(const double* __restrict__ uhat,
                                                 const double* __restrict__ cij,
                                                 double* __restrict__ sj) {
  int bl = blockIdx.x, j = blockIdx.y;
  int tid = threadIdx.x;
  int o = tid & 15, cl = tid >> 4;
  double acc = 0.0;
  const double* up = uhat + (size_t)bl * 1152 * 160 + j * 16 + o;
  if (IT == 0) {
    for (int c = cl; c < 1152; c += 16) acc += 0.1 * up[(size_t)c * 160];
  } else {
    const double* cp = cij + (size_t)bl * 1152 * 10 + j;
    for (int c = cl; c < 1152; c += 16) acc += cp[(size_t)c * 10] * up[(size_t)c * 160];
  }
  __shared__ double red[256];
  red[tid] = acc;
  __syncthreads();
#pragma unroll
  for (int s = 128; s >= 16; s >>= 1) {
    if (tid < s) red[tid] += red[tid + s];
    __syncthreads();
  }
  if (tid < 16) sj[(size_t)bl * 160 + j * 16 + tid] = red[tid];
}

// ---------------- agreement update b_ij fp64, wide grid -------------------------
template <bool FIRST>
__global__ __launch_bounds__(256) void k_route_b(const double* __restrict__ uhat,
                                                 const double* __restrict__ sj,
                                                 double* __restrict__ bij) {
  __shared__ double sl[160];
  int bl = blockIdx.x;
  int tid = threadIdx.x;
  if (tid < 160) sl[tid] = sj[(size_t)bl * 160 + tid];
  __syncthreads();
  int c = blockIdx.y * 128 + (tid >> 1);
  int j0 = (tid & 1) * 5;
  const double* up = uhat + ((size_t)bl * 1152 + c) * 160;
  double* bp_ = bij + ((size_t)bl * 1152 + c) * 10;
#pragma unroll
  for (int jj = 0; jj < 5; jj++) {
    int j = j0 + jj;
    double dot = 0.0;
#pragma unroll
    for (int oo = 0; oo < 16; oo++) dot += sl[j * 16 + oo] * up[j * 16 + oo];
    bp_[j] = (FIRST ? 0.0 : bp_[j]) + dot;
  }
}

// ---------------- epilogue: np-fp32-canonical (verbatim passing chain) ----------
__global__ __launch_bounds__(192) void k_epi(const double* __restrict__ sj,
                                             float* __restrict__ vout,
                                             float* __restrict__ idxout, int b0) {
#pragma clang fp contract(off)
  __shared__ float vsh[160];
  __shared__ float len32[10];
  int bl = blockIdx.x;
  int tid = threadIdx.x;
  const double* sp = sj + (size_t)bl * 160;
  if (tid < 10) {
    float s32[16], a[16];
#pragma unroll
    for (int o = 0; o < 16; o++) { s32[o] = (float)sp[tid * 16 + o]; a[o] = s32[o] * s32[o]; }
    float r[8];
#pragma unroll
    for (int k = 0; k < 8; k++) r[k] = a[k] + a[k + 8];
    float ns = ((r[0] + r[1]) + (r[2] + r[3])) + ((r[4] + r[5]) + (r[6] + r[7]));
    float A = ns / (1.0f + ns);
    float D = 0.001f + sqrtf(ns);
#pragma unroll
    for (int o = 0; o < 16; o++) {
      float v = A * (s32[o] / D);
      vsh[tid * 16 + o] = v;
      a[o] = v * v;
    }
#pragma unroll
    for (int k = 0; k < 8; k++) r[k] = a[k] + a[k + 8];
    float nv = ((r[0] + r[1]) + (r[2] + r[3])) + ((r[4] + r[5]) + (r[6] + r[7]));
    len32[tid] = sqrtf(nv);
  }
  __syncthreads();
  if (tid < 160) vout[(size_t)(b0 + bl) * 160 + tid] = vsh[tid];
  if (tid == 0) {
    float mx = len32[0];
    for (int jj = 1; jj < 10; jj++) mx = fmaxf(mx, len32[jj]);
    float e[10];
    for (int jj = 0; jj < 10; jj++) e[jj] = (float)exp((double)(len32[jj] - mx));
    float ssum = ((e[0] + e[1]) + (e[2] + e[3])) + ((e[4] + e[5]) + (e[6] + e[7]));
    ssum = ssum + e[8];
    ssum = ssum + e[9];
    int best = 0;
    float bst = e[0] / ssum;
    for (int jj = 1; jj < 10; jj++) {
      float p = e[jj] / ssum;
      if (p > bst) { bst = p; best = jj; }
    }
    idxout[b0 + bl] = (float)best;
  }
}

// ---------------- decoder layer 1 (masked input has only 16 nonzeros) -----------
__global__ __launch_bounds__(256) void k_z1(const float* __restrict__ vout,
                                            const int* __restrict__ targets,
                                            const float* __restrict__ W1,
                                            const float* __restrict__ b1,
                                            float* __restrict__ z1) {
  int id = blockIdx.x * 256 + threadIdx.x;
  int b = id >> 9, n = id & 511;
  int t = targets[b];
  float acc = b1[n];
  const float* wr = W1 + (size_t)n * 160 + t * 16;
  const float* vr = vout + (size_t)b * 160 + t * 16;
#pragma unroll
  for (int o = 0; o < 16; o++) acc += wr[o] * vr[o];
  z1[id] = fmaxf(acc, 0.f);
}

// ---------------- generic fp32 GEMM: out[b,n] = act(Z[b,:]·W[n,:] + bias[n]) ----
template <int ACT>
__global__ __launch_bounds__(256) void k_gemm_act(const float* __restrict__ Z,
                                                  const float* __restrict__ W,
                                                  const float* __restrict__ bias,
                                                  float* __restrict__ out, int N, int K) {
  __shared__ float Zt[64][17];
  __shared__ float Wt[64][17];
  int b0 = blockIdx.x * 64;
  int n0 = blockIdx.y * 64;
  int tid = threadIdx.x;
  int ty = tid >> 4, tx = tid & 15;
  int lr = tid >> 2, lc = (tid & 3) * 4;
  float acc[4][4] = {};
  for (int k0 = 0; k0 < K; k0 += 16) {
    __syncthreads();
    f32x4 zv = *(const f32x4*)(Z + (size_t)(b0 + lr) * K + k0 + lc);
    f32x4 wv = {0.f, 0.f, 0.f, 0.f};
    if (n0 + lr < N) wv = *(const f32x4*)(W + (size_t)(n0 + lr) * K + k0 + lc);
    Zt[lr][lc + 0] = zv.x; Zt[lr][lc + 1] = zv.y; Zt[lr][lc + 2] = zv.z; Zt[lr][lc + 3] = zv.w;
    Wt[lr][lc + 0] = wv.x; Wt[lr][lc + 1] = wv.y; Wt[lr][lc + 2] = wv.z; Wt[lr][lc + 3] = wv.w;
    __syncthreads();
#pragma unroll
    for (int kk = 0; kk < 16; kk++) {
      float av[4], bw[4];
#pragma unroll
      for (int i = 0; i < 4; i++) av[i] = Zt[ty * 4 + i][kk];
#pragma unroll
      for (int i = 0; i < 4; i++) bw[i] = Wt[tx * 4 + i][kk];
#pragma unroll
      for (int i = 0; i < 4; i++)
#pragma unroll
        for (int jj = 0; jj < 4; jj++) acc[i][jj] += av[i] * bw[jj];
    }
  }
#pragma unroll
  for (int i = 0; i < 4; i++)
#pragma unroll
    for (int jj = 0; jj < 4; jj++) {
      int bb = b0 + ty * 4 + i;
      int n = n0 + tx * 4 + jj;
      if (n < N) {
        float v = acc[i][jj] + bias[n];
        out[(size_t)bb * N + n] = (ACT == 0) ? fmaxf(v, 0.f) : 1.f / (1.f + __expf(-v));
      }
    }
}

extern "C" void kernel_launch(void* const* d_in, const int* in_sizes, int n_in,
                              void* d_out, int out_size, void* d_ws, size_t ws_size,
                              hipStream_t stream) {
  const float* x       = (const float*)d_in[0];
  const int* targets   = (const int*)d_in[1];
  const float* Wc      = (const float*)d_in[2];
  const float* bc      = (const float*)d_in[3];
  const float* Wp      = (const float*)d_in[4];
  const float* bp      = (const float*)d_in[5];
  const float* Wd      = (const float*)d_in[6];
  const float* W1      = (const float*)d_in[7];
  const float* b1      = (const float*)d_in[8];
  const float* W2      = (const float*)d_in[9];
  const float* b2      = (const float*)d_in[10];
  const float* W3      = (const float*)d_in[11];
  const float* b3      = (const float*)d_in[12];

  char* ws = (char*)d_ws;
  const size_t MB = 1024 * 1024;
  // Conv phase (thirds of <=172 imgs):
  //   wT32 [0, 20.25)    fp32 [k][n] weights
  //   h64  [21, 148.3)   19x19x256 f64 per image, chunk-local
  //   u64  [149, 185)    conv2 out full batch -> squashed in place
  //   flag [208, 208+4)  MFMA layout probe result
  // Peak 208 MiB (proven-safe envelope: 213).
  float* wT32 = (float*)ws;
  double* h64 = (double*)(ws + 21 * MB);
  double* u64 = (double*)(ws + 149 * MB);
  int* flagp  = (int*)(ws + 208 * MB);
  // Routing phase (wT32/h64 dead): all below 149 MiB.
  double* uhat64 = (double*)(ws);             // 90   [0,90)
  double* bij64  = (double*)(ws + 90 * MB);   // 5.63 [90,96)
  double* cij64  = (double*)(ws + 96 * MB);   // 5.63 [96,102)
  double* sj64   = (double*)(ws + 102 * MB);  // 0.08
  float* z1      = (float*)(ws + 103 * MB);   // 1 MiB
  float* z2      = (float*)(ws + 104 * MB);   // 2 MiB

  float* vout   = (float*)d_out;                  // [512,10,16]
  float* recon  = (float*)d_out + 81920;          // [512,784]
  float* idxout = (float*)d_out + 81920 + 401408; // [512]

  k_probe<<<1, 64, 0, stream>>>(flagp);
  k_wkn<<<4096, 256, 0, stream>>>(Wp, wT32);
  // 3 chunks of 6144 m-rows (<=172 imgs): 192 m-tiles(32) x 4 n-tiles = 768 blocks
  const int iLo[3] = {0, 170, 341};
  const int iHi[3] = {171, 342, 512};
  for (int L = 0; L < 3; L++) {
    int cnt = iHi[L] - iLo[L];
    k_conv1_19<<<cnt * 2, 256, 0, stream>>>(x + (size_t)iLo[L] * 784, Wc, bc, h64);
    k_conv2_m<<<dim3(192, 4), 128, 0, stream>>>(h64, wT32, u64, flagp, 6144 * L, iLo[L]);
  }
  k_squash_ip<<<2304, 256, 0, stream>>>(u64, bp);
  for (int e = 0; e < 8; e++) {
    int b0 = e * 64;
    k_uhat64<<<1152, 320, 0, stream>>>(u64, Wd, uhat64, b0);
    k_route_s<0><<<dim3(64, 10), 256, 0, stream>>>(uhat64, cij64, sj64);
    k_route_b<true><<<dim3(64, 9), 256, 0, stream>>>(uhat64, sj64, bij64);
    k_cij<<<dim3(64, 6), 192, 0, stream>>>(bij64, cij64);
    k_route_s<1><<<dim3(64, 10), 256, 0, stream>>>(uhat64, cij64, sj64);
    k_route_b<false><<<dim3(64, 9), 256, 0, stream>>>(uhat64, sj64, bij64);
    k_cij<<<dim3(64, 6), 192, 0, stream>>>(bij64, cij64);
    k_route_s<2><<<dim3(64, 10), 256, 0, stream>>>(uhat64, cij64, sj64);
    k_epi<<<64, 192, 0, stream>>>(sj64, vout, idxout, b0);
  }
  k_z1<<<1024, 256, 0, stream>>>(vout, targets, W1, b1, z1);
  k_gemm_act<0><<<dim3(8, 16), 256, 0, stream>>>(z1, W2, b2, z2, 1024, 512);
  k_gemm_act<1><<<dim3(8, 13), 256, 0, stream>>>(z2, W3, b3, recon, 784, 1024);
}

// Round 9
// 5628.964 us; speedup vs baseline: 1.6058x; 1.6058x over previous
//
#include <hip/hip_runtime.h>
#include <math.h>

typedef __attribute__((ext_vector_type(2))) double f64x2;
typedef __attribute__((ext_vector_type(4))) double f64x4;
typedef __attribute__((ext_vector_type(2))) float f32x2;
typedef __attribute__((ext_vector_type(4))) float f32x4;

// ---------------- probe: discover v_mfma_f64_16x16x4 D-fragment mapping --------
// A[m][k] = 1+m+17k, B[k][n] = 2+3k+5n (asymmetric, exact small ints).
// Candidate D mappings (g=lane>>4, c=lane&15, reg r):
//   1: D[4g+r][c]   2: D[g+4r][c]   3: D[c][4g+r]   4: D[c][g+4r]
// flag = matching mapping, or 0 -> conv2 uses VALU fallback (always correct).
__global__ __launch_bounds__(64) void k_probe(int* __restrict__ flag) {
  int l = threadIdx.x;
  int g = l >> 4, c = l & 15;
  double a = 1.0 + (double)(l & 15) + 17.0 * (double)(l >> 4);      // A[m=l%16][k=l/16]
  double b = 2.0 + 3.0 * (double)(l >> 4) + 5.0 * (double)(l & 15); // B[k=l/16][n=l%16]
  f64x4 d = {0.0, 0.0, 0.0, 0.0};
  d = __builtin_amdgcn_mfma_f64_16x16x4f64(a, b, d, 0, 0, 0);
  auto ref = [](int R, int C) -> double {
    double s = 0.0;
    for (int k = 0; k < 4; k++) s += (1.0 + R + 17.0 * k) * (2.0 + 3.0 * k + 5.0 * C);
    return s;
  };
  int ok1 = 1, ok2 = 1, ok3 = 1, ok4 = 1;
#pragma unroll
  for (int r = 0; r < 4; r++) {
    double v = d[r];
    ok1 &= (v == ref(g * 4 + r, c));
    ok2 &= (v == ref(g + 4 * r, c));
    ok3 &= (v == ref(c, g * 4 + r));
    ok4 &= (v == ref(c, g + 4 * r));
  }
  ok1 = __all(ok1); ok2 = __all(ok2); ok3 = __all(ok3); ok4 = __all(ok4);
  if (l == 0) *flag = ok1 ? 1 : (ok2 ? 2 : (ok3 ? 3 : (ok4 ? 4 : 0)));
}

// ---------------- Wp -> wT fp32, layout [k][n], k=(ky*9+kx)*256+ci --------------
__global__ __launch_bounds__(256) void k_wkn(const float* __restrict__ Wp,
                                             float* __restrict__ wT) {
  const int total = 20736 * 256;
  for (int gid = blockIdx.x * 256 + threadIdx.x; gid < total; gid += gridDim.x * 256) {
    int k = gid >> 8, n = gid & 255;
    int t = k >> 8, ci = k & 255;
    wT[gid] = Wp[(size_t)n * 20736 + ci * 81 + t];
  }
}

// ---------------- Conv1: 1->256 k9 s1, fp64, out [img][y][x][256], 19x19 --------
__global__ __launch_bounds__(256) void k_conv1_19(const float* __restrict__ x,
                                                  const float* __restrict__ Wc,
                                                  const float* __restrict__ bc,
                                                  double* __restrict__ h) {
  int b = blockIdx.x >> 1;
  int rh = (blockIdx.x & 1) * 10;
  int re = rh ? 19 : 10;
  int oc = threadIdx.x;
  __shared__ float xs[784];
  for (int i = threadIdx.x; i < 784; i += 256) xs[i] = x[(size_t)b * 784 + i];
  __syncthreads();
  float w[81];
#pragma unroll
  for (int t = 0; t < 81; t++) w[t] = Wc[(size_t)oc * 81 + t];
  double bias = (double)bc[oc];
  for (int oh = rh; oh < re; oh++) {
    for (int ow4 = 0; ow4 < 20; ow4 += 4) {
      double a0 = bias, a1 = bias, a2 = bias, a3 = bias;
#pragma unroll
      for (int ky = 0; ky < 9; ky++) {
        const float* xr = &xs[(oh + ky) * 28 + ow4];
#pragma unroll
        for (int kx = 0; kx < 9; kx++) {
          double wv = (double)w[ky * 9 + kx];
          a0 += wv * (double)xr[kx + 0];
          a1 += wv * (double)xr[kx + 1];
          a2 += wv * (double)xr[kx + 2];
          a3 += wv * (double)xr[kx + 3];
        }
      }
      size_t base = ((size_t)(b * 19 + oh) * 19 + ow4) * 256 + oc;
      h[base + 0]   = fmax(a0, 0.0);
      h[base + 256] = fmax(a1, 0.0);
      h[base + 512] = fmax(a2, 0.0);
      if (ow4 < 16) h[base + 768] = fmax(a3, 0.0);  // skip col 19
    }
  }
}

// ---------------- Conv2: f64 MFMA implicit GEMM, 4 waves/block ------------------
// Tile 64m x 32n, 256 thr (4 waves, each 16m x 32n = 8 MFMA/ks).
// Grid thirds: dim3(96,8) = 768 blocks = exactly 3 blocks/CU -> 12 waves/CU
// (3 waves/SIMD: MFMA issue from one wave overlaps LDS/barrier of the others).
// LDS: A f64 [k][m] pad 66 (m up to 63! -- R8's bug was pad 34), B f64 [k][n]
// pad 34 (n up to 31). flag==0 -> VALU fallback (same staging, always correct).
__global__ __launch_bounds__(256, 3) void k_conv2_m2(const double* __restrict__ h,
                                                     const float* __restrict__ wT,
                                                     double* __restrict__ uraw,
                                                     const int* __restrict__ flagp,
                                                     int mG0, int imgLo) {
  __shared__ __align__(16) double As[2][16][66];
  __shared__ __align__(16) double Bs[2][16][34];
  int tid = threadIdx.x;
  int m0 = blockIdx.x * 64, n0 = blockIdx.y * 32;

  // A staging: thread -> (m row tid&63, 4 consecutive k at (tid>>6)*4)
  int ma = tid & 63, kqa = tid >> 6;
  int mGa = mG0 + m0 + ma;
  int imga = mGa / 36, spa = mGa % 36;
  size_t abase = ((size_t)((imga - imgLo) * 361 + (spa / 6) * 38 + (spa % 6) * 2)) * 256;
  const double* hrow = h + abase;
  // B staging: thread -> (k row tid>>4, 2 consecutive n at (tid&15)*2)
  int kb = tid >> 4, np2 = (tid & 15) * 2;
  // fragment coords
  int w = tid >> 6, lane = tid & 63;
  int fl = lane & 15, fk = lane >> 4;
  int flag = *flagp;  // uniform

  f64x2 pa0, pa1;
  f32x2 pb;
  auto loadreg = [&](int ks) {
    int t = ks >> 4, ci0 = (ks & 15) * 16;
    const double* ga = hrow + (size_t)((t / 9) * 19 + (t % 9)) * 256 + ci0 + kqa * 4;
    pa0 = *(const f64x2*)ga;
    pa1 = *(const f64x2*)(ga + 2);
    pb = *(const f32x2*)(wT + (size_t)(ks * 16 + kb) * 256 + n0 + np2);
  };
  auto writebuf = [&](int buf) {
    As[buf][kqa * 4 + 0][ma] = pa0.x;
    As[buf][kqa * 4 + 1][ma] = pa0.y;
    As[buf][kqa * 4 + 2][ma] = pa1.x;
    As[buf][kqa * 4 + 3][ma] = pa1.y;
    Bs[buf][kb][np2 + 0] = (double)pb.x;
    Bs[buf][kb][np2 + 1] = (double)pb.y;
  };

  loadreg(0);
  writebuf(0);
  loadreg(1);
  __syncthreads();

  if (flag) {
    f64x4 acc0 = {0, 0, 0, 0}, acc1 = {0, 0, 0, 0};
    int mwl = w * 16 + fl;
    int cur = 0;
    for (int ks = 0; ks < 1296; ks++) {
      if (ks + 1 < 1296) writebuf(cur ^ 1);  // safe: end-of-prev-iter barrier
      if (ks + 2 < 1296) loadreg(ks + 2);
#pragma unroll
      for (int kq = 0; kq < 4; kq++) {
        int row = kq * 4 + fk;
        double a = As[cur][row][mwl];
        double b0 = Bs[cur][row][fl];
        double b1 = Bs[cur][row][16 + fl];
        acc0 = __builtin_amdgcn_mfma_f64_16x16x4f64(a, b0, acc0, 0, 0, 0);
        acc1 = __builtin_amdgcn_mfma_f64_16x16x4f64(a, b1, acc1, 0, 0, 0);
      }
      __syncthreads();
      cur ^= 1;
    }
    f64x4 accs[2] = {acc0, acc1};
#pragma unroll
    for (int nt = 0; nt < 2; nt++) {
#pragma unroll
      for (int r = 0; r < 4; r++) {
        int rb = (flag == 1 || flag == 3) ? (fk * 4 + r) : (fk + 4 * r);
        int R = (flag <= 2) ? rb : fl;
        int C = (flag <= 2) ? fl : rb;
        int mG = mG0 + m0 + w * 16 + R;
        int img = mG / 36, sp = mG % 36;
        int n = n0 + nt * 16 + C;
        uraw[(size_t)img * 9216 + (size_t)n * 36 + sp] = accs[nt][r];
      }
    }
  } else {
    // VALU fallback: thread tile 2m x 4n, k ascending sequential fma
    int ty = tid >> 3, tx = tid & 7;
    double acc[2][4];
#pragma unroll
    for (int i = 0; i < 2; i++)
#pragma unroll
      for (int j = 0; j < 4; j++) acc[i][j] = 0.0;
    int cur = 0;
    for (int ks = 0; ks < 1296; ks++) {
      if (ks + 1 < 1296) writebuf(cur ^ 1);
      if (ks + 2 < 1296) loadreg(ks + 2);
#pragma unroll
      for (int kk = 0; kk < 16; kk++) {
        f64x2 av = *(const f64x2*)&As[cur][kk][ty * 2];
        f64x2 b01 = *(const f64x2*)&Bs[cur][kk][tx * 4];
        f64x2 b23 = *(const f64x2*)&Bs[cur][kk][tx * 4 + 2];
        acc[0][0] = fma(av.x, b01.x, acc[0][0]);
        acc[0][1] = fma(av.x, b01.y, acc[0][1]);
        acc[0][2] = fma(av.x, b23.x, acc[0][2]);
        acc[0][3] = fma(av.x, b23.y, acc[0][3]);
        acc[1][0] = fma(av.y, b01.x, acc[1][0]);
        acc[1][1] = fma(av.y, b01.y, acc[1][1]);
        acc[1][2] = fma(av.y, b23.x, acc[1][2]);
        acc[1][3] = fma(av.y, b23.y, acc[1][3]);
      }
      __syncthreads();
      cur ^= 1;
    }
#pragma unroll
    for (int i = 0; i < 2; i++) {
      int mG = mG0 + m0 + ty * 2 + i;
      int img = mG / 36, sp = mG % 36;
#pragma unroll
      for (int j = 0; j < 4; j++) {
        int n = n0 + tx * 4 + j;
        uraw[(size_t)img * 9216 + (size_t)n * 36 + sp] = acc[i][j];
      }
    }
  }
}

// ---------------- squash of primary capsules, fp64, IN PLACE --------------------
__global__ __launch_bounds__(256) void k_squash_ip(double* __restrict__ u,
                                                   const float* __restrict__ bp) {
  int idx = blockIdx.x * 256 + threadIdx.x;  // (b,c): 512*1152
  int bl = idx / 1152, c = idx % 1152;
  size_t base = ((size_t)bl * 1152 + c) * 8;
  double v[8];
  double ns = 0.0;
#pragma unroll
  for (int i = 0; i < 8; i++) {
    int f = c * 8 + i;
    int ch = f / 36;
    double val = u[base + i] + (double)bp[ch];
    v[i] = val;
    ns += val * val;
  }
  double sc = (ns / (1.0 + ns)) / (0.001 + sqrt(ns));
#pragma unroll
  for (int i = 0; i < 8; i++) u[base + i] = v[i] * sc;
}

// ---------------- u_hat fp64, eighth batch (bl in [0,64)) -----------------------
__global__ __launch_bounds__(320) void k_uhat64(const double* __restrict__ u,
                                                const float* __restrict__ Wd,
                                                double* __restrict__ uhat, int b0) {
  int c = blockIdx.x;
  int t = threadIdx.x;
  int jo = t % 160, half = t / 160;
  double w[8];
#pragma unroll
  for (int i = 0; i < 8; i++) w[i] = (double)Wd[((size_t)c * 160 + jo) * 8 + i];
  for (int it = 0; it < 32; it++) {
    int bl = it * 2 + half;
    const double* up = u + ((size_t)(b0 + bl) * 1152 + c) * 8;
    double s = 0.0;
#pragma unroll
    for (int i = 0; i < 8; i++) s += w[i] * up[i];
    uhat[((size_t)bl * 1152 + c) * 160 + jo] = s;
  }
}

// ---------------- c_ij = softmax(b_ij) fp64, wide grid --------------------------
__global__ __launch_bounds__(192) void k_cij(const double* __restrict__ bij,
                                             double* __restrict__ cij) {
  int bl = blockIdx.x;
  int c = blockIdx.y * 192 + threadIdx.x;  // 6*192 = 1152
  const double* bp_ = bij + ((size_t)bl * 1152 + c) * 10;
  double bv[10], mx = -1e300;
#pragma unroll
  for (int j = 0; j < 10; j++) { bv[j] = bp_[j]; mx = fmax(mx, bv[j]); }
  double s = 0.0;
#pragma unroll
  for (int j = 0; j < 10; j++) { bv[j] = exp(bv[j] - mx); s += bv[j]; }
  double inv = 1.0 / s;
  double* cp = cij + ((size_t)bl * 1152 + c) * 10;
#pragma unroll
  for (int j = 0; j < 10; j++) cp[j] = bv[j] * inv;
}

// ---------------- routing s_j pass fp64, wide coalesced grid (bl x j) -----------
template <int IT>
__global__ __launch_bounds__(256) void k_route_s(const double* __restrict__ uhat,
                                                 const double* __restrict__ cij,
                                                 double* __restrict__ sj) {
  int bl = blockIdx.x, j = blockIdx.y;
  int tid = threadIdx.x;
  int o = tid & 15, cl = tid >> 4;
  double acc = 0.0;
  const double* up = uhat + (size_t)bl * 1152 * 160 + j * 16 + o;
  if (IT == 0) {
    for (int c = cl; c < 1152; c += 16) acc += 0.1 * up[(size_t)c * 160];
  } else {
    const double* cp = cij + (size_t)bl * 1152 * 10 + j;
    for (int c = cl; c < 1152; c += 16) acc += cp[(size_t)c * 10] * up[(size_t)c * 160];
  }
  __shared__ double red[256];
  red[tid] = acc;
  __syncthreads();
#pragma unroll
  for (int s = 128; s >= 16; s >>= 1) {
    if (tid < s) red[tid] += red[tid + s];
    __syncthreads();
  }
  if (tid < 16) sj[(size_t)bl * 160 + j * 16 + tid] = red[tid];
}

// ---------------- agreement update b_ij fp64, wide grid -------------------------
template <bool FIRST>
__global__ __launch_bounds__(256) void k_route_b(const double* __restrict__ uhat,
                                                 const double* __restrict__ sj,
                                                 double* __restrict__ bij) {
  __shared__ double sl[160];
  int bl = blockIdx.x;
  int tid = threadIdx.x;
  if (tid < 160) sl[tid] = sj[(size_t)bl * 160 + tid];
  __syncthreads();
  int c = blockIdx.y * 128 + (tid >> 1);
  int j0 = (tid & 1) * 5;
  const double* up = uhat + ((size_t)bl * 1152 + c) * 160;
  double* bp_ = bij + ((size_t)bl * 1152 + c) * 10;
#pragma unroll
  for (int jj = 0; jj < 5; jj++) {
    int j = j0 + jj;
    double dot = 0.0;
#pragma unroll
    for (int oo = 0; oo < 16; oo++) dot += sl[j * 16 + oo] * up[j * 16 + oo];
    bp_[j] = (FIRST ? 0.0 : bp_[j]) + dot;
  }
}

// ---------------- epilogue: np-fp32-canonical (verbatim passing chain) ----------
__global__ __launch_bounds__(192) void k_epi(const double* __restrict__ sj,
                                             float* __restrict__ vout,
                                             float* __restrict__ idxout, int b0) {
#pragma clang fp contract(off)
  __shared__ float vsh[160];
  __shared__ float len32[10];
  int bl = blockIdx.x;
  int tid = threadIdx.x;
  const double* sp = sj + (size_t)bl * 160;
  if (tid < 10) {
    float s32[16], a[16];
#pragma unroll
    for (int o = 0; o < 16; o++) { s32[o] = (float)sp[tid * 16 + o]; a[o] = s32[o] * s32[o]; }
    float r[8];
#pragma unroll
    for (int k = 0; k < 8; k++) r[k] = a[k] + a[k + 8];
    float ns = ((r[0] + r[1]) + (r[2] + r[3])) + ((r[4] + r[5]) + (r[6] + r[7]));
    float A = ns / (1.0f + ns);
    float D = 0.001f + sqrtf(ns);
#pragma unroll
    for (int o = 0; o < 16; o++) {
      float v = A * (s32[o] / D);
      vsh[tid * 16 + o] = v;
      a[o] = v * v;
    }
#pragma unroll
    for (int k = 0; k < 8; k++) r[k] = a[k] + a[k + 8];
    float nv = ((r[0] + r[1]) + (r[2] + r[3])) + ((r[4] + r[5]) + (r[6] + r[7]));
    len32[tid] = sqrtf(nv);
  }
  __syncthreads();
  if (tid < 160) vout[(size_t)(b0 + bl) * 160 + tid] = vsh[tid];
  if (tid == 0) {
    float mx = len32[0];
    for (int jj = 1; jj < 10; jj++) mx = fmaxf(mx, len32[jj]);
    float e[10];
    for (int jj = 0; jj < 10; jj++) e[jj] = (float)exp((double)(len32[jj] - mx));
    float ssum = ((e[0] + e[1]) + (e[2] + e[3])) + ((e[4] + e[5]) + (e[6] + e[7]));
    ssum = ssum + e[8];
    ssum = ssum + e[9];
    int best = 0;
    float bst = e[0] / ssum;
    for (int jj = 1; jj < 10; jj++) {
      float p = e[jj] / ssum;
      if (p > bst) { bst = p; best = jj; }
    }
    idxout[b0 + bl] = (float)best;
  }
}

// ---------------- decoder layer 1 (masked input has only 16 nonzeros) -----------
__global__ __launch_bounds__(256) void k_z1(const float* __restrict__ vout,
                                            const int* __restrict__ targets,
                                            const float* __restrict__ W1,
                                            const float* __restrict__ b1,
                                            float* __restrict__ z1) {
  int id = blockIdx.x * 256 + threadIdx.x;
  int b = id >> 9, n = id & 511;
  int t = targets[b];
  float acc = b1[n];
  const float* wr = W1 + (size_t)n * 160 + t * 16;
  const float* vr = vout + (size_t)b * 160 + t * 16;
#pragma unroll
  for (int o = 0; o < 16; o++) acc += wr[o] * vr[o];
  z1[id] = fmaxf(acc, 0.f);
}

// ---------------- generic fp32 GEMM: out[b,n] = act(Z[b,:]·W[n,:] + bias[n]) ----
template <int ACT>
__global__ __launch_bounds__(256) void k_gemm_act(const float* __restrict__ Z,
                                                  const float* __restrict__ W,
                                                  const float* __restrict__ bias,
                                                  float* __restrict__ out, int N, int K) {
  __shared__ float Zt[64][17];
  __shared__ float Wt[64][17];
  int b0 = blockIdx.x * 64;
  int n0 = blockIdx.y * 64;
  int tid = threadIdx.x;
  int ty = tid >> 4, tx = tid & 15;
  int lr = tid >> 2, lc = (tid & 3) * 4;
  float acc[4][4] = {};
  for (int k0 = 0; k0 < K; k0 += 16) {
    __syncthreads();
    f32x4 zv = *(const f32x4*)(Z + (size_t)(b0 + lr) * K + k0 + lc);
    f32x4 wv = {0.f, 0.f, 0.f, 0.f};
    if (n0 + lr < N) wv = *(const f32x4*)(W + (size_t)(n0 + lr) * K + k0 + lc);
    Zt[lr][lc + 0] = zv.x; Zt[lr][lc + 1] = zv.y; Zt[lr][lc + 2] = zv.z; Zt[lr][lc + 3] = zv.w;
    Wt[lr][lc + 0] = wv.x; Wt[lr][lc + 1] = wv.y; Wt[lr][lc + 2] = wv.z; Wt[lr][lc + 3] = wv.w;
    __syncthreads();
#pragma unroll
    for (int kk = 0; kk < 16; kk++) {
      float av[4], bw[4];
#pragma unroll
      for (int i = 0; i < 4; i++) av[i] = Zt[ty * 4 + i][kk];
#pragma unroll
      for (int i = 0; i < 4; i++) bw[i] = Wt[tx * 4 + i][kk];
#pragma unroll
      for (int i = 0; i < 4; i++)
#pragma unroll
        for (int jj = 0; jj < 4; jj++) acc[i][jj] += av[i] * bw[jj];
    }
  }
#pragma unroll
  for (int i = 0; i < 4; i++)
#pragma unroll
    for (int jj = 0; jj < 4; jj++) {
      int bb = b0 + ty * 4 + i;
      int n = n0 + tx * 4 + jj;
      if (n < N) {
        float v = acc[i][jj] + bias[n];
        out[(size_t)bb * N + n] = (ACT == 0) ? fmaxf(v, 0.f) : 1.f / (1.f + __expf(-v));
      }
    }
}

extern "C" void kernel_launch(void* const* d_in, const int* in_sizes, int n_in,
                              void* d_out, int out_size, void* d_ws, size_t ws_size,
                              hipStream_t stream) {
  const float* x       = (const float*)d_in[0];
  const int* targets   = (const int*)d_in[1];
  const float* Wc      = (const float*)d_in[2];
  const float* bc      = (const float*)d_in[3];
  const float* Wp      = (const float*)d_in[4];
  const float* bp      = (const float*)d_in[5];
  const float* Wd      = (const float*)d_in[6];
  const float* W1      = (const float*)d_in[7];
  const float* b1      = (const float*)d_in[8];
  const float* W2      = (const float*)d_in[9];
  const float* b2      = (const float*)d_in[10];
  const float* W3      = (const float*)d_in[11];
  const float* b3      = (const float*)d_in[12];

  char* ws = (char*)d_ws;
  const size_t MB = 1024 * 1024;
  // Conv phase (thirds of <=172 imgs):
  //   wT32 [0, 20.25)    fp32 [k][n] weights
  //   h64  [21, 148.3)   19x19x256 f64 per image, chunk-local
  //   u64  [149, 185)    conv2 out full batch -> squashed in place
  //   flag [208, 208+4)  MFMA layout probe result
  // Peak 208 MiB (proven-safe envelope: 213).
  float* wT32 = (float*)ws;
  double* h64 = (double*)(ws + 21 * MB);
  double* u64 = (double*)(ws + 149 * MB);
  int* flagp  = (int*)(ws + 208 * MB);
  // Routing phase (wT32/h64 dead): all below 149 MiB.
  double* uhat64 = (double*)(ws);             // 90   [0,90)
  double* bij64  = (double*)(ws + 90 * MB);   // 5.63 [90,96)
  double* cij64  = (double*)(ws + 96 * MB);   // 5.63 [96,102)
  double* sj64   = (double*)(ws + 102 * MB);  // 0.08
  float* z1      = (float*)(ws + 103 * MB);   // 1 MiB
  float* z2      = (float*)(ws + 104 * MB);   // 2 MiB

  float* vout   = (float*)d_out;                  // [512,10,16]
  float* recon  = (float*)d_out + 81920;          // [512,784]
  float* idxout = (float*)d_out + 81920 + 401408; // [512]

  k_probe<<<1, 64, 0, stream>>>(flagp);
  k_wkn<<<4096, 256, 0, stream>>>(Wp, wT32);
  // 3 chunks of 6144 m-rows (<=172 imgs): 96 m-tiles(64) x 8 n-tiles(32) = 768 blocks
  const int iLo[3] = {0, 170, 341};
  const int iHi[3] = {171, 342, 512};
  for (int L = 0; L < 3; L++) {
    int cnt = iHi[L] - iLo[L];
    k_conv1_19<<<cnt * 2, 256, 0, stream>>>(x + (size_t)iLo[L] * 784, Wc, bc, h64);
    k_conv2_m2<<<dim3(96, 8), 256, 0, stream>>>(h64, wT32, u64, flagp, 6144 * L, iLo[L]);
  }
  k_squash_ip<<<2304, 256, 0, stream>>>(u64, bp);
  for (int e = 0; e < 8; e++) {
    int b0 = e * 64;
    k_uhat64<<<1152, 320, 0, stream>>>(u64, Wd, uhat64, b0);
    k_route_s<0><<<dim3(64, 10), 256, 0, stream>>>(uhat64, cij64, sj64);
    k_route_b<true><<<dim3(64, 9), 256, 0, stream>>>(uhat64, sj64, bij64);
    k_cij<<<dim3(64, 6), 192, 0, stream>>>(bij64, cij64);
    k_route_s<1><<<dim3(64, 10), 256, 0, stream>>>(uhat64, cij64, sj64);
    k_route_b<false><<<dim3(64, 9), 256, 0, stream>>>(uhat64, sj64, bij64);
    k_cij<<<dim3(64, 6), 192, 0, stream>>>(bij64, cij64);
    k_route_s<2><<<dim3(64, 10), 256, 0, stream>>>(uhat64, cij64, sj64);
    k_epi<<<64, 192, 0, stream>>>(sj64, vout, idxout, b0);
  }
  k_z1<<<1024, 256, 0, stream>>>(vout, targets, W1, b1, z1);
  k_gemm_act<0><<<dim3(8, 16), 256, 0, stream>>>(z1, W2, b2, z2, 1024, 512);
  k_gemm_act<1><<<dim3(8, 13), 256, 0, stream>>>(z2, W3, b3, recon, 784, 1024);
}

// Round 10
// 5394.364 us; speedup vs baseline: 1.6756x; 1.0435x over previous
//
#include <hip/hip_runtime.h>
#include <math.h>

typedef __attribute__((ext_vector_type(2))) double f64x2;
typedef __attribute__((ext_vector_type(4))) double f64x4;
typedef __attribute__((ext_vector_type(2))) float f32x2;
typedef __attribute__((ext_vector_type(4))) float f32x4;

// ---------------- probe: discover v_mfma_f64_16x16x4 D-fragment mapping --------
// A[m][k] = 1+m+17k, B[k][n] = 2+3k+5n (asymmetric, exact small ints).
// Candidate D mappings (g=lane>>4, c=lane&15, reg r):
//   1: D[4g+r][c]   2: D[g+4r][c]   3: D[c][4g+r]   4: D[c][g+4r]
// flag = matching mapping, or 0 -> conv2 uses VALU fallback (always correct).
__global__ __launch_bounds__(64) void k_probe(int* __restrict__ flag) {
  int l = threadIdx.x;
  int g = l >> 4, c = l & 15;
  double a = 1.0 + (double)(l & 15) + 17.0 * (double)(l >> 4);      // A[m=l%16][k=l/16]
  double b = 2.0 + 3.0 * (double)(l >> 4) + 5.0 * (double)(l & 15); // B[k=l/16][n=l%16]
  f64x4 d = {0.0, 0.0, 0.0, 0.0};
  d = __builtin_amdgcn_mfma_f64_16x16x4f64(a, b, d, 0, 0, 0);
  auto ref = [](int R, int C) -> double {
    double s = 0.0;
    for (int k = 0; k < 4; k++) s += (1.0 + R + 17.0 * k) * (2.0 + 3.0 * k + 5.0 * C);
    return s;
  };
  int ok1 = 1, ok2 = 1, ok3 = 1, ok4 = 1;
#pragma unroll
  for (int r = 0; r < 4; r++) {
    double v = d[r];
    ok1 &= (v == ref(g * 4 + r, c));
    ok2 &= (v == ref(g + 4 * r, c));
    ok3 &= (v == ref(c, g * 4 + r));
    ok4 &= (v == ref(c, g + 4 * r));
  }
  ok1 = __all(ok1); ok2 = __all(ok2); ok3 = __all(ok3); ok4 = __all(ok4);
  if (l == 0) *flag = ok1 ? 1 : (ok2 ? 2 : (ok3 ? 3 : (ok4 ? 4 : 0)));
}

// ---------------- Wp -> wT fp32, layout [k][n], k=(ky*9+kx)*256+ci --------------
__global__ __launch_bounds__(256) void k_wkn(const float* __restrict__ Wp,
                                             float* __restrict__ wT) {
  const int total = 20736 * 256;
  for (int gid = blockIdx.x * 256 + threadIdx.x; gid < total; gid += gridDim.x * 256) {
    int k = gid >> 8, n = gid & 255;
    int t = k >> 8, ci = k & 255;
    wT[gid] = Wp[(size_t)n * 20736 + ci * 81 + t];
  }
}

// ---------------- Conv1: 1->256 k9 s1, fp64, out [img][y][x][256], 19x19 --------
__global__ __launch_bounds__(256) void k_conv1_19(const float* __restrict__ x,
                                                  const float* __restrict__ Wc,
                                                  const float* __restrict__ bc,
                                                  double* __restrict__ h) {
  int b = blockIdx.x >> 1;
  int rh = (blockIdx.x & 1) * 10;
  int re = rh ? 19 : 10;
  int oc = threadIdx.x;
  __shared__ float xs[784];
  for (int i = threadIdx.x; i < 784; i += 256) xs[i] = x[(size_t)b * 784 + i];
  __syncthreads();
  float w[81];
#pragma unroll
  for (int t = 0; t < 81; t++) w[t] = Wc[(size_t)oc * 81 + t];
  double bias = (double)bc[oc];
  for (int oh = rh; oh < re; oh++) {
    for (int ow4 = 0; ow4 < 20; ow4 += 4) {
      double a0 = bias, a1 = bias, a2 = bias, a3 = bias;
#pragma unroll
      for (int ky = 0; ky < 9; ky++) {
        const float* xr = &xs[(oh + ky) * 28 + ow4];
#pragma unroll
        for (int kx = 0; kx < 9; kx++) {
          double wv = (double)w[ky * 9 + kx];
          a0 += wv * (double)xr[kx + 0];
          a1 += wv * (double)xr[kx + 1];
          a2 += wv * (double)xr[kx + 2];
          a3 += wv * (double)xr[kx + 3];
        }
      }
      size_t base = ((size_t)(b * 19 + oh) * 19 + ow4) * 256 + oc;
      h[base + 0]   = fmax(a0, 0.0);
      h[base + 256] = fmax(a1, 0.0);
      h[base + 512] = fmax(a2, 0.0);
      if (ow4 < 16) h[base + 768] = fmax(a3, 0.0);  // skip col 19
    }
  }
}

// ---------------- Conv2: f64 MFMA implicit GEMM, BK=32, 4 waves/block -----------
// Tile 64m x 32n, 256 thr (4 waves, each 16m x 32n = 16 MFMA/iter at BK=32).
// Grid thirds: dim3(96,8) = 768 blocks = exactly 3 blocks/CU -> 12 waves/CU.
// BK=32 halves the per-iteration barrier/latency overhead vs R9's BK=16
// (648 iterations). LDS = 50 KiB/block (A [32][66], B [32][34], dbuf) -> 3/CU.
// flag==0 -> VALU fallback (same staging, always correct).
__global__ __launch_bounds__(256, 3) void k_conv2_m3(const double* __restrict__ h,
                                                     const float* __restrict__ wT,
                                                     double* __restrict__ uraw,
                                                     const int* __restrict__ flagp,
                                                     int mG0, int imgLo) {
  __shared__ __align__(16) double As[2][32][66];
  __shared__ __align__(16) double Bs[2][32][34];
  int tid = threadIdx.x;
  int m0 = blockIdx.x * 64, n0 = blockIdx.y * 32;

  // A staging: thread -> (m row tid&63, 8 consecutive k at (tid>>6)*8)
  int ma = tid & 63, ko = (tid >> 6) * 8;
  int mGa = mG0 + m0 + ma;
  int imga = mGa / 36, spa = mGa % 36;
  size_t abase = ((size_t)((imga - imgLo) * 361 + (spa / 6) * 38 + (spa % 6) * 2)) * 256;
  const double* hrow = h + abase;
  // B staging: thread -> (k row tid>>3, 4 consecutive n at (tid&7)*4)
  int kb = tid >> 3, n4 = (tid & 7) * 4;
  // fragment coords
  int w = tid >> 6, lane = tid & 63;
  int fl = lane & 15, fk = lane >> 4;
  int flag = *flagp;  // uniform

  f64x2 pa[4];
  f32x4 pb;
  // iteration ks covers global k = t*256 + ci0 + [0,32), t = ks>>3, ci0 = (ks&7)*32
  auto loadreg = [&](int ks) {
    int t = ks >> 3, ci0 = (ks & 7) * 32;
    const double* ga = hrow + (size_t)((t / 9) * 19 + (t % 9)) * 256 + ci0 + ko;
    pa[0] = *(const f64x2*)ga;
    pa[1] = *(const f64x2*)(ga + 2);
    pa[2] = *(const f64x2*)(ga + 4);
    pa[3] = *(const f64x2*)(ga + 6);
    pb = *(const f32x4*)(wT + (size_t)(ks * 32 + kb) * 256 + n0 + n4);
  };
  auto writebuf = [&](int buf) {
#pragma unroll
    for (int j = 0; j < 4; j++) {
      As[buf][ko + 2 * j + 0][ma] = pa[j].x;
      As[buf][ko + 2 * j + 1][ma] = pa[j].y;
    }
    Bs[buf][kb][n4 + 0] = (double)pb.x;
    Bs[buf][kb][n4 + 1] = (double)pb.y;
    Bs[buf][kb][n4 + 2] = (double)pb.z;
    Bs[buf][kb][n4 + 3] = (double)pb.w;
  };

  loadreg(0);
  writebuf(0);
  loadreg(1);
  __syncthreads();

  if (flag) {
    f64x4 acc0 = {0, 0, 0, 0}, acc1 = {0, 0, 0, 0};
    int mwl = w * 16 + fl;
    int cur = 0;
    for (int ks = 0; ks < 648; ks++) {
      if (ks + 1 < 648) writebuf(cur ^ 1);  // safe: end-of-prev-iter barrier
      if (ks + 2 < 648) loadreg(ks + 2);
#pragma unroll
      for (int kq = 0; kq < 8; kq++) {
        int row = kq * 4 + fk;
        double a = As[cur][row][mwl];
        double b0 = Bs[cur][row][fl];
        double b1 = Bs[cur][row][16 + fl];
        acc0 = __builtin_amdgcn_mfma_f64_16x16x4f64(a, b0, acc0, 0, 0, 0);
        acc1 = __builtin_amdgcn_mfma_f64_16x16x4f64(a, b1, acc1, 0, 0, 0);
      }
      __syncthreads();
      cur ^= 1;
    }
    f64x4 accs[2] = {acc0, acc1};
#pragma unroll
    for (int nt = 0; nt < 2; nt++) {
#pragma unroll
      for (int r = 0; r < 4; r++) {
        int rb = (flag == 1 || flag == 3) ? (fk * 4 + r) : (fk + 4 * r);
        int R = (flag <= 2) ? rb : fl;
        int C = (flag <= 2) ? fl : rb;
        int mG = mG0 + m0 + w * 16 + R;
        int img = mG / 36, sp = mG % 36;
        int n = n0 + nt * 16 + C;
        uraw[(size_t)img * 9216 + (size_t)n * 36 + sp] = accs[nt][r];
      }
    }
  } else {
    // VALU fallback: thread tile 2m x 4n, k ascending sequential fma
    int ty = tid >> 3, tx = tid & 7;
    double acc[2][4];
#pragma unroll
    for (int i = 0; i < 2; i++)
#pragma unroll
      for (int j = 0; j < 4; j++) acc[i][j] = 0.0;
    int cur = 0;
    for (int ks = 0; ks < 648; ks++) {
      if (ks + 1 < 648) writebuf(cur ^ 1);
      if (ks + 2 < 648) loadreg(ks + 2);
#pragma unroll
      for (int kk = 0; kk < 32; kk++) {
        f64x2 av = *(const f64x2*)&As[cur][kk][ty * 2];
        f64x2 b01 = *(const f64x2*)&Bs[cur][kk][tx * 4];
        f64x2 b23 = *(const f64x2*)&Bs[cur][kk][tx * 4 + 2];
        acc[0][0] = fma(av.x, b01.x, acc[0][0]);
        acc[0][1] = fma(av.x, b01.y, acc[0][1]);
        acc[0][2] = fma(av.x, b23.x, acc[0][2]);
        acc[0][3] = fma(av.x, b23.y, acc[0][3]);
        acc[1][0] = fma(av.y, b01.x, acc[1][0]);
        acc[1][1] = fma(av.y, b01.y, acc[1][1]);
        acc[1][2] = fma(av.y, b23.x, acc[1][2]);
        acc[1][3] = fma(av.y, b23.y, acc[1][3]);
      }
      __syncthreads();
      cur ^= 1;
    }
#pragma unroll
    for (int i = 0; i < 2; i++) {
      int mG = mG0 + m0 + ty * 2 + i;
      int img = mG / 36, sp = mG % 36;
#pragma unroll
      for (int j = 0; j < 4; j++) {
        int n = n0 + tx * 4 + j;
        uraw[(size_t)img * 9216 + (size_t)n * 36 + sp] = acc[i][j];
      }
    }
  }
}

// ---------------- squash of primary capsules, fp64, IN PLACE --------------------
__global__ __launch_bounds__(256) void k_squash_ip(double* __restrict__ u,
                                                   const float* __restrict__ bp) {
  int idx = blockIdx.x * 256 + threadIdx.x;  // (b,c): 512*1152
  int bl = idx / 1152, c = idx % 1152;
  size_t base = ((size_t)bl * 1152 + c) * 8;
  double v[8];
  double ns = 0.0;
#pragma unroll
  for (int i = 0; i < 8; i++) {
    int f = c * 8 + i;
    int ch = f / 36;
    double val = u[base + i] + (double)bp[ch];
    v[i] = val;
    ns += val * val;
  }
  double sc = (ns / (1.0 + ns)) / (0.001 + sqrt(ns));
#pragma unroll
  for (int i = 0; i < 8; i++) u[base + i] = v[i] * sc;
}

// ---------------- u_hat fp64, eighth batch (bl in [0,64)) -----------------------
__global__ __launch_bounds__(320) void k_uhat64(const double* __restrict__ u,
                                                const float* __restrict__ Wd,
                                                double* __restrict__ uhat, int b0) {
  int c = blockIdx.x;
  int t = threadIdx.x;
  int jo = t % 160, half = t / 160;
  double w[8];
#pragma unroll
  for (int i = 0; i < 8; i++) w[i] = (double)Wd[((size_t)c * 160 + jo) * 8 + i];
  for (int it = 0; it < 32; it++) {
    int bl = it * 2 + half;
    const double* up = u + ((size_t)(b0 + bl) * 1152 + c) * 8;
    double s = 0.0;
#pragma unroll
    for (int i = 0; i < 8; i++) s += w[i] * up[i];
    uhat[((size_t)bl * 1152 + c) * 160 + jo] = s;
  }
}

// ---------------- routing s_j pass fp64, wide coalesced grid (bl x j) -----------
template <int IT>
__global__ __launch_bounds__(256) void k_route_s(const double* __restrict__ uhat,
                                                 const double* __restrict__ cij,
                                                 double* __restrict__ sj) {
  int bl = blockIdx.x, j = blockIdx.y;
  int tid = threadIdx.x;
  int o = tid & 15, cl = tid >> 4;
  double acc = 0.0;
  const double* up = uhat + (size_t)bl * 1152 * 160 + j * 16 + o;
  if (IT == 0) {
    for (int c = cl; c < 1152; c += 16) acc += 0.1 * up[(size_t)c * 160];
  } else {
    const double* cp = cij + (size_t)bl * 1152 * 10 + j;
    for (int c = cl; c < 1152; c += 16) acc += cp[(size_t)c * 10] * up[(size_t)c * 160];
  }
  __shared__ double red[256];
  red[tid] = acc;
  __syncthreads();
#pragma unroll
  for (int s = 128; s >= 16; s >>= 1) {
    if (tid < s) red[tid] += red[tid + s];
    __syncthreads();
  }
  if (tid < 16) sj[(size_t)bl * 160 + j * 16 + tid] = red[tid];
}

// ---------------- fused agreement update + softmax (route_b + cij) --------------
// Thread pair (tid, tid^1) covers capsule c's j in [0,5) and [5,10).
// Dot chain identical to the passing k_route_b; softmax max is exact (order-free);
// pair-split exp-sum reorders the 10-term sum by ~1e-16 (proven-safe scale).
template <bool FIRST>
__global__ __launch_bounds__(256) void k_route_bc(const double* __restrict__ uhat,
                                                  const double* __restrict__ sj,
                                                  double* __restrict__ bij,
                                                  double* __restrict__ cij) {
  __shared__ double sl[160];
  int bl = blockIdx.x;
  int tid = threadIdx.x;
  if (tid < 160) sl[tid] = sj[(size_t)bl * 160 + tid];
  __syncthreads();
  int c = blockIdx.y * 128 + (tid >> 1);
  int j0 = (tid & 1) * 5;
  const double* up = uhat + ((size_t)bl * 1152 + c) * 160;
  double* bp_ = bij + ((size_t)bl * 1152 + c) * 10;
  double bv[5];
#pragma unroll
  for (int jj = 0; jj < 5; jj++) {
    int j = j0 + jj;
    double dot = 0.0;
#pragma unroll
    for (int oo = 0; oo < 16; oo++) dot += sl[j * 16 + oo] * up[j * 16 + oo];
    bv[jj] = (FIRST ? 0.0 : bp_[j]) + dot;
    bp_[j] = bv[jj];
  }
  double mx = bv[0];
#pragma unroll
  for (int jj = 1; jj < 5; jj++) mx = fmax(mx, bv[jj]);
  mx = fmax(mx, __shfl_xor(mx, 1));
  double s = 0.0;
#pragma unroll
  for (int jj = 0; jj < 5; jj++) { bv[jj] = exp(bv[jj] - mx); s += bv[jj]; }
  s += __shfl_xor(s, 1);
  double inv = 1.0 / s;
  double* cp = cij + ((size_t)bl * 1152 + c) * 10;
#pragma unroll
  for (int jj = 0; jj < 5; jj++) cp[j0 + jj] = bv[jj] * inv;
}

// ---------------- epilogue: np-fp32-canonical (verbatim passing chain) ----------
__global__ __launch_bounds__(192) void k_epi(const double* __restrict__ sj,
                                             float* __restrict__ vout,
                                             float* __restrict__ idxout, int b0) {
#pragma clang fp contract(off)
  __shared__ float vsh[160];
  __shared__ float len32[10];
  int bl = blockIdx.x;
  int tid = threadIdx.x;
  const double* sp = sj + (size_t)bl * 160;
  if (tid < 10) {
    float s32[16], a[16];
#pragma unroll
    for (int o = 0; o < 16; o++) { s32[o] = (float)sp[tid * 16 + o]; a[o] = s32[o] * s32[o]; }
    float r[8];
#pragma unroll
    for (int k = 0; k < 8; k++) r[k] = a[k] + a[k + 8];
    float ns = ((r[0] + r[1]) + (r[2] + r[3])) + ((r[4] + r[5]) + (r[6] + r[7]));
    float A = ns / (1.0f + ns);
    float D = 0.001f + sqrtf(ns);
#pragma unroll
    for (int o = 0; o < 16; o++) {
      float v = A * (s32[o] / D);
      vsh[tid * 16 + o] = v;
      a[o] = v * v;
    }
#pragma unroll
    for (int k = 0; k < 8; k++) r[k] = a[k] + a[k + 8];
    float nv = ((r[0] + r[1]) + (r[2] + r[3])) + ((r[4] + r[5]) + (r[6] + r[7]));
    len32[tid] = sqrtf(nv);
  }
  __syncthreads();
  if (tid < 160) vout[(size_t)(b0 + bl) * 160 + tid] = vsh[tid];
  if (tid == 0) {
    float mx = len32[0];
    for (int jj = 1; jj < 10; jj++) mx = fmaxf(mx, len32[jj]);
    float e[10];
    for (int jj = 0; jj < 10; jj++) e[jj] = (float)exp((double)(len32[jj] - mx));
    float ssum = ((e[0] + e[1]) + (e[2] + e[3])) + ((e[4] + e[5]) + (e[6] + e[7]));
    ssum = ssum + e[8];
    ssum = ssum + e[9];
    int best = 0;
    float bst = e[0] / ssum;
    for (int jj = 1; jj < 10; jj++) {
      float p = e[jj] / ssum;
      if (p > bst) { bst = p; best = jj; }
    }
    idxout[b0 + bl] = (float)best;
  }
}

// ---------------- decoder layer 1 (masked input has only 16 nonzeros) -----------
__global__ __launch_bounds__(256) void k_z1(const float* __restrict__ vout,
                                            const int* __restrict__ targets,
                                            const float* __restrict__ W1,
                                            const float* __restrict__ b1,
                                            float* __restrict__ z1) {
  int id = blockIdx.x * 256 + threadIdx.x;
  int b = id >> 9, n = id & 511;
  int t = targets[b];
  float acc = b1[n];
  const float* wr = W1 + (size_t)n * 160 + t * 16;
  const float* vr = vout + (size_t)b * 160 + t * 16;
#pragma unroll
  for (int o = 0; o < 16; o++) acc += wr[o] * vr[o];
  z1[id] = fmaxf(acc, 0.f);
}

// ---------------- generic fp32 GEMM: out[b,n] = act(Z[b,:]·W[n,:] + bias[n]) ----
template <int ACT>
__global__ __launch_bounds__(256) void k_gemm_act(const float* __restrict__ Z,
                                                  const float* __restrict__ W,
                                                  const float* __restrict__ bias,
                                                  float* __restrict__ out, int N, int K) {
  __shared__ float Zt[64][17];
  __shared__ float Wt[64][17];
  int b0 = blockIdx.x * 64;
  int n0 = blockIdx.y * 64;
  int tid = threadIdx.x;
  int ty = tid >> 4, tx = tid & 15;
  int lr = tid >> 2, lc = (tid & 3) * 4;
  float acc[4][4] = {};
  for (int k0 = 0; k0 < K; k0 += 16) {
    __syncthreads();
    f32x4 zv = *(const f32x4*)(Z + (size_t)(b0 + lr) * K + k0 + lc);
    f32x4 wv = {0.f, 0.f, 0.f, 0.f};
    if (n0 + lr < N) wv = *(const f32x4*)(W + (size_t)(n0 + lr) * K + k0 + lc);
    Zt[lr][lc + 0] = zv.x; Zt[lr][lc + 1] = zv.y; Zt[lr][lc + 2] = zv.z; Zt[lr][lc + 3] = zv.w;
    Wt[lr][lc + 0] = wv.x; Wt[lr][lc + 1] = wv.y; Wt[lr][lc + 2] = wv.z; Wt[lr][lc + 3] = wv.w;
    __syncthreads();
#pragma unroll
    for (int kk = 0; kk < 16; kk++) {
      float av[4], bw[4];
#pragma unroll
      for (int i = 0; i < 4; i++) av[i] = Zt[ty * 4 + i][kk];
#pragma unroll
      for (int i = 0; i < 4; i++) bw[i] = Wt[tx * 4 + i][kk];
#pragma unroll
      for (int i = 0; i < 4; i++)
#pragma unroll
        for (int jj = 0; jj < 4; jj++) acc[i][jj] += av[i] * bw[jj];
    }
  }
#pragma unroll
  for (int i = 0; i < 4; i++)
#pragma unroll
    for (int jj = 0; jj < 4; jj++) {
      int bb = b0 + ty * 4 + i;
      int n = n0 + tx * 4 + jj;
      if (n < N) {
        float v = acc[i][jj] + bias[n];
        out[(size_t)bb * N + n] = (ACT == 0) ? fmaxf(v, 0.f) : 1.f / (1.f + __expf(-v));
      }
    }
}

extern "C" void kernel_launch(void* const* d_in, const int* in_sizes, int n_in,
                              void* d_out, int out_size, void* d_ws, size_t ws_size,
                              hipStream_t stream) {
  const float* x       = (const float*)d_in[0];
  const int* targets   = (const int*)d_in[1];
  const float* Wc      = (const float*)d_in[2];
  const float* bc      = (const float*)d_in[3];
  const float* Wp      = (const float*)d_in[4];
  const float* bp      = (const float*)d_in[5];
  const float* Wd      = (const float*)d_in[6];
  const float* W1      = (const float*)d_in[7];
  const float* b1      = (const float*)d_in[8];
  const float* W2      = (const float*)d_in[9];
  const float* b2      = (const float*)d_in[10];
  const float* W3      = (const float*)d_in[11];
  const float* b3      = (const float*)d_in[12];

  char* ws = (char*)d_ws;
  const size_t MB = 1024 * 1024;
  // Conv phase (thirds of <=172 imgs):
  //   wT32 [0, 20.25)    fp32 [k][n] weights
  //   h64  [21, 148.3)   19x19x256 f64 per image, chunk-local
  //   u64  [149, 185)    conv2 out full batch -> squashed in place
  //   flag [208, 208+4)  MFMA layout probe result
  // Peak 208 MiB (proven-safe envelope: 213).
  float* wT32 = (float*)ws;
  double* h64 = (double*)(ws + 21 * MB);
  double* u64 = (double*)(ws + 149 * MB);
  int* flagp  = (int*)(ws + 208 * MB);
  // Routing phase (wT32/h64 dead): all below 149 MiB.
  double* uhat64 = (double*)(ws);             // 90   [0,90)
  double* bij64  = (double*)(ws + 90 * MB);   // 5.63 [90,96)
  double* cij64  = (double*)(ws + 96 * MB);   // 5.63 [96,102)
  double* sj64   = (double*)(ws + 102 * MB);  // 0.08
  float* z1      = (float*)(ws + 103 * MB);   // 1 MiB
  float* z2      = (float*)(ws + 104 * MB);   // 2 MiB

  float* vout   = (float*)d_out;                  // [512,10,16]
  float* recon  = (float*)d_out + 81920;          // [512,784]
  float* idxout = (float*)d_out + 81920 + 401408; // [512]

  k_probe<<<1, 64, 0, stream>>>(flagp);
  k_wkn<<<4096, 256, 0, stream>>>(Wp, wT32);
  // 3 chunks of 6144 m-rows (<=172 imgs): 96 m-tiles(64) x 8 n-tiles(32) = 768 blocks
  const int iLo[3] = {0, 170, 341};
  const int iHi[3] = {171, 342, 512};
  for (int L = 0; L < 3; L++) {
    int cnt = iHi[L] - iLo[L];
    k_conv1_19<<<cnt * 2, 256, 0, stream>>>(x + (size_t)iLo[L] * 784, Wc, bc, h64);
    k_conv2_m3<<<dim3(96, 8), 256, 0, stream>>>(h64, wT32, u64, flagp, 6144 * L, iLo[L]);
  }
  k_squash_ip<<<2304, 256, 0, stream>>>(u64, bp);
  for (int e = 0; e < 8; e++) {
    int b0 = e * 64;
    k_uhat64<<<1152, 320, 0, stream>>>(u64, Wd, uhat64, b0);
    k_route_s<0><<<dim3(64, 10), 256, 0, stream>>>(uhat64, cij64, sj64);
    k_route_bc<true><<<dim3(64, 9), 256, 0, stream>>>(uhat64, sj64, bij64, cij64);
    k_route_s<1><<<dim3(64, 10), 256, 0, stream>>>(uhat64, cij64, sj64);
    k_route_bc<false><<<dim3(64, 9), 256, 0, stream>>>(uhat64, sj64, bij64, cij64);
    k_route_s<2><<<dim3(64, 10), 256, 0, stream>>>(uhat64, cij64, sj64);
    k_epi<<<64, 192, 0, stream>>>(sj64, vout, idxout, b0);
  }
  k_z1<<<1024, 256, 0, stream>>>(vout, targets, W1, b1, z1);
  k_gemm_act<0><<<dim3(8, 16), 256, 0, stream>>>(z1, W2, b2, z2, 1024, 512);
  k_gemm_act<1><<<dim3(8, 13), 256, 0, stream>>>(z2, W3, b3, recon, 784, 1024);
}